// Round 1
// baseline (27859.265 us; speedup 1.0000x reference)
//
#include <hip/hip_runtime.h>
#include <cmath>

// Problem dims
#define B_  32
#define T_  512
#define D_  512
#define Q_  1024
#define G_  4096   // 4*Q
#define TC  32     // timestep chunk
#define NCHUNK (T_/TC)

// ---------------------------------------------------------------------------
// zero a float region
__global__ void zero_kernel(float* __restrict__ p, int n) {
    int i = blockIdx.x * blockDim.x + threadIdx.x;
    if (i < n) p[i] = 0.f;
}

// ---------------------------------------------------------------------------
// pre[m, n] = sum_k A[row(m), k] * W[n, k] + bih[n] + bhh[n]
// m in [0,1024): m = b*TC + tt ; A row = b*TA + t0 + tt (row-major, stride K)
// W is [4096, K] row-major. pre is [1024, 4096] (i.e. [B][TC][G]).
// BM=BN=128, BK=16, 256 threads, 8x8 micro-tile.
__global__ __launch_bounds__(256) void gemm_pre(
    const float* __restrict__ A, const float* __restrict__ W,
    const float* __restrict__ bih, const float* __restrict__ bhh,
    float* __restrict__ pre, int K, int TA, int t0)
{
    __shared__ __align__(16) float As[16][132];
    __shared__ __align__(16) float Bs[16][132];
    const int tid = threadIdx.x;
    const int tx = tid & 15, ty = tid >> 4;
    const int m0 = blockIdx.y * 128, n0 = blockIdx.x * 128;

    float acc[8][8];
#pragma unroll
    for (int i = 0; i < 8; ++i)
#pragma unroll
        for (int j = 0; j < 8; ++j) acc[i][j] = 0.f;

    for (int k0 = 0; k0 < K; k0 += 16) {
        // stage A (128 rows x 16 k) and W (128 n x 16 k), transposed into LDS
#pragma unroll
        for (int r = 0; r < 2; ++r) {
            int idx = tid + r * 256;          // 0..511
            int row = idx >> 2;               // 0..127
            int kq  = (idx & 3) << 2;         // 0,4,8,12
            int m = m0 + row;
            int bb = m >> 5, tt = m & 31;     // TC == 32
            const float* ap = A + (size_t)(bb * TA + t0 + tt) * K + k0 + kq;
            float4 av = *(const float4*)ap;
            As[kq + 0][row] = av.x; As[kq + 1][row] = av.y;
            As[kq + 2][row] = av.z; As[kq + 3][row] = av.w;
            const float* wp = W + (size_t)(n0 + row) * K + k0 + kq;
            float4 wv = *(const float4*)wp;
            Bs[kq + 0][row] = wv.x; Bs[kq + 1][row] = wv.y;
            Bs[kq + 2][row] = wv.z; Bs[kq + 3][row] = wv.w;
        }
        __syncthreads();
#pragma unroll
        for (int k = 0; k < 16; ++k) {
            float a[8], bv[8];
#pragma unroll
            for (int i = 0; i < 8; ++i) a[i] = As[k][ty * 8 + i];
#pragma unroll
            for (int j = 0; j < 4; ++j) {
                bv[j]     = Bs[k][tx * 4 + j];
                bv[4 + j] = Bs[k][64 + tx * 4 + j];
            }
#pragma unroll
            for (int i = 0; i < 8; ++i)
#pragma unroll
                for (int j = 0; j < 8; ++j)
                    acc[i][j] = fmaf(a[i], bv[j], acc[i][j]);
        }
        __syncthreads();
    }

    // epilogue: add (bih + bhh), store
    const int n1 = n0 + tx * 4;
    const int n2 = n0 + 64 + tx * 4;
    float bias1[4], bias2[4];
#pragma unroll
    for (int j = 0; j < 4; ++j) {
        bias1[j] = bih[n1 + j] + bhh[n1 + j];
        bias2[j] = bih[n2 + j] + bhh[n2 + j];
    }
#pragma unroll
    for (int i = 0; i < 8; ++i) {
        int m = m0 + ty * 8 + i;
        float* prow = pre + (size_t)m * G_;
        float4 o1, o2;
        o1.x = acc[i][0] + bias1[0]; o1.y = acc[i][1] + bias1[1];
        o1.z = acc[i][2] + bias1[2]; o1.w = acc[i][3] + bias1[3];
        o2.x = acc[i][4] + bias2[0]; o2.y = acc[i][5] + bias2[1];
        o2.z = acc[i][6] + bias2[2]; o2.w = acc[i][7] + bias2[3];
        *(float4*)(prow + n1) = o1;
        *(float4*)(prow + n2) = o2;
    }
}

// ---------------------------------------------------------------------------
// One LSTM timestep. 512 WGs x 256 threads; WG owns q in [2*wg, 2*wg+2)
// i.e. 8 gate columns. gates = pre[b][tt][col] + sum_k h_in[b][k]*whh[col][k]
// (biases already folded into pre). Updates c_st, writes h_out and yout.
__global__ __launch_bounds__(256) void lstm_step(
    const float* __restrict__ pre, int tt,
    const float* __restrict__ whh,
    const float* __restrict__ h_in, float* __restrict__ h_out,
    float* __restrict__ c_st,
    float* __restrict__ yout, int yT, int yt)
{
    __shared__ __align__(16) float w_s[8 * 1024];   // 8 gate cols x K=1024
    __shared__ __align__(16) float h_s[32 * 132];   // 32 b x 128 k (+pad); reused for reduce
    const int tid = threadIdx.x;
    const int q0 = blockIdx.x * 2;

    // stage weights: local col c = ql*4+g  ->  global row g*Q + q0 + ql
#pragma unroll
    for (int r = 0; r < 8; ++r) {
        int f4 = tid + r * 256;       // 0..2047
        int c  = f4 >> 8;             // 0..7
        int k4 = (f4 & 255) << 2;     // 0..1020
        int ql = c >> 2, g = c & 3;
        int grow = g * Q_ + q0 + ql;
        float4 v = *(const float4*)(whh + (size_t)grow * Q_ + k4);
        *(float4*)&w_s[c * 1024 + k4] = v;
    }

    const int b  = tid & 31;
    const int ql = (tid >> 5) & 1;
    const int hk = tid >> 6;          // 0..3, K quarter
    float acc[4] = {0.f, 0.f, 0.f, 0.f};

    for (int kc = 0; kc < 8; ++kc) {  // 8 chunks of 128 k
        // stage h chunk: conflict-free float4 stores (consecutive lanes -> consecutive k4)
#pragma unroll
        for (int r = 0; r < 4; ++r) {
            int f4  = tid + r * 256;      // 0..1023
            int row = f4 >> 5;            // 0..31
            int k4  = (f4 & 31) << 2;     // 0..124
            float4 v = *(const float4*)(h_in + (size_t)row * Q_ + kc * 128 + k4);
            *(float4*)&h_s[row * 132 + k4] = v;
        }
        __syncthreads();
        const float* hrow = &h_s[b * 132 + hk * 32];
        const int wk = kc * 128 + hk * 32;
#pragma unroll
        for (int kk = 0; kk < 32; kk += 4) {
            float4 hv = *(const float4*)&hrow[kk];
#pragma unroll
            for (int g = 0; g < 4; ++g) {
                float4 wv = *(const float4*)&w_s[(ql * 4 + g) * 1024 + wk + kk];
                acc[g] = fmaf(hv.x, wv.x, acc[g]);
                acc[g] = fmaf(hv.y, wv.y, acc[g]);
                acc[g] = fmaf(hv.z, wv.z, acc[g]);
                acc[g] = fmaf(hv.w, wv.w, acc[g]);
            }
        }
        __syncthreads();  // protect h_s before restage / reuse
    }

    // reduce the 4 K-quarters via LDS (alias h_s)
    float* red = h_s;
    *(float4*)&red[tid * 4] = make_float4(acc[0], acc[1], acc[2], acc[3]);
    __syncthreads();

    if (tid < 64) {
        float g0 = 0.f, g1 = 0.f, g2 = 0.f, g3 = 0.f;
#pragma unroll
        for (int h = 0; h < 4; ++h) {
            const float* rp = &red[(tid + 64 * h) * 4];
            g0 += rp[0]; g1 += rp[1]; g2 += rp[2]; g3 += rp[3];
        }
        const int bb  = tid & 31;
        const int qll = tid >> 5;
        const int q   = q0 + qll;
        const float* prow = pre + ((size_t)bb * TC + tt) * G_;
        float gi = g0 + prow[q];
        float gf = g1 + prow[Q_ + q];
        float gg = g2 + prow[2 * Q_ + q];
        float go = g3 + prow[3 * Q_ + q];
        float i_ = 1.f / (1.f + expf(-gi));
        float f_ = 1.f / (1.f + expf(-gf));
        float g_ = tanhf(gg);
        float o_ = 1.f / (1.f + expf(-go));
        float c_old = c_st[bb * Q_ + q];
        float c_new = f_ * c_old + i_ * g_;
        float h_new = o_ * tanhf(c_new);
        c_st[bb * Q_ + q] = c_new;
        h_out[bb * Q_ + q] = h_new;
        yout[((size_t)bb * yT + yt) * Q_ + q] = h_new;
    }
}

// ---------------------------------------------------------------------------
__global__ void copy_hc(const float* __restrict__ h, const float* __restrict__ c,
                        float* __restrict__ dst)
{
    int i = blockIdx.x * blockDim.x + threadIdx.x;   // 0..65535
    if (i < 32768) dst[i] = h[i];
    else           dst[i] = c[i - 32768];
}

// ---------------------------------------------------------------------------
extern "C" void kernel_launch(void* const* d_in, const int* in_sizes, int n_in,
                              void* d_out, int out_size, void* d_ws, size_t ws_size,
                              hipStream_t stream)
{
    const float* x    = (const float*)d_in[0];  // [32,512,512]
    const float* wih0 = (const float*)d_in[1];  // [4096,512]
    const float* whh0 = (const float*)d_in[2];  // [4096,1024]
    const float* bih0 = (const float*)d_in[3];
    const float* bhh0 = (const float*)d_in[4];
    const float* wih1 = (const float*)d_in[5];  // [4096,1024]
    const float* whh1 = (const float*)d_in[6];  // [4096,1024]
    const float* bih1 = (const float*)d_in[7];
    const float* bhh1 = (const float*)d_in[8];
    float* out = (float*)d_out;                  // y1 [32,512,1024] ++ h[32,1024] ++ c[32,1024]
    float* ws  = (float*)d_ws;

    float* pre0 = ws;                  // 4,194,304 floats  ([B][TC][4096])
    float* pre1 = ws + 4194304;        // 4,194,304
    float* y0c  = ws + 8388608;        // 1,048,576  ([B][TC][1024])
    float* st   = ws + 9437184;        // states: 6 x 32768
    float* h0a = st;            float* h0b = st + 32768;
    float* c0  = st + 65536;
    float* h1a = st + 98304;    float* h1b = st + 131072;
    float* c1  = st + 163840;          // total ws = 9,633,792 floats (~38.5 MB)

    // zero all state buffers (ws is poisoned 0xAA before every call)
    hipLaunchKernelGGL(zero_kernel, dim3(768), dim3(256), 0, stream, st, 196608);

    for (int ch = 0; ch < NCHUNK; ++ch) {
        const int t0 = ch * TC;
        // layer-0 input projection for this chunk: x slice -> pre0
        hipLaunchKernelGGL(gemm_pre, dim3(32, 8), dim3(256), 0, stream,
                           x, wih0, bih0, bhh0, pre0, 512, 512, t0);
        for (int tt = 0; tt < TC; ++tt) {
            const int t = t0 + tt;
            const float* hin = (t & 1) ? h0b : h0a;
            float* hout      = (t & 1) ? h0a : h0b;
            hipLaunchKernelGGL(lstm_step, dim3(512), dim3(256), 0, stream,
                               pre0, tt, whh0, hin, hout, c0, y0c, TC, tt);
        }
        // layer-1 input projection for this chunk: y0c -> pre1
        hipLaunchKernelGGL(gemm_pre, dim3(32, 8), dim3(256), 0, stream,
                           y0c, wih1, bih1, bhh1, pre1, 1024, 32, 0);
        for (int tt = 0; tt < TC; ++tt) {
            const int t = t0 + tt;
            const float* hin = (t & 1) ? h1b : h1a;
            float* hout      = (t & 1) ? h1a : h1b;
            hipLaunchKernelGGL(lstm_step, dim3(512), dim3(256), 0, stream,
                               pre1, tt, whh1, hin, hout, c1, out, T_, t);
        }
    }
    // final (h, c) tail: T=512 even -> last write went to the 'a' buffer
    hipLaunchKernelGGL(copy_hc, dim3(256), dim3(256), 0, stream,
                       h1a, c1, out + 16777216);
}